// Round 8
// baseline (186.388 us; speedup 1.0000x reference)
//
#include <hip/hip_runtime.h>

#define BB 32
#define CC 64
#define NN 1024

typedef __attribute__((ext_vector_type(8))) short bf8;            // 8 bf16 = 4 VGPR (MFMA A/B frag)
typedef __attribute__((ext_vector_type(4))) float f4;             // MFMA C/D frag
typedef __attribute__((ext_vector_type(4))) unsigned short us4;   // 8B packed bf16 store

__device__ __forceinline__ unsigned short f2bf(float f) {
    unsigned u = __float_as_uint(f);
    return (unsigned short)((u + 0x7fffu + ((u >> 16) & 1u)) >> 16);
}

#define MFMA(a, b, c) __builtin_amdgcn_mfma_f32_16x16x32_bf16(a, b, c, 0, 0, 0)

// Async global->LDS DMA, 16 B per lane: LDS dst = wave-uniform base + lane*16.
#define GLDS(g, l)                                                              \
    __builtin_amdgcn_global_load_lds(                                           \
        (const __attribute__((address_space(1))) void*)(g),                     \
        (__attribute__((address_space(3))) void*)(l), 16, 0, 0)

// ---------------------------------------------------------------------------
// k0: wcat_bf[192][64] = [w_theta; w_phi; wall] bf16, where
// wall = w_mask @ w_mv @ w_g (mask epilogue folded through mv,g).
// ---------------------------------------------------------------------------
__global__ __launch_bounds__(1024) void k0_prep(const float* __restrict__ w_mv,
                                                const float* __restrict__ w_g,
                                                const float* __restrict__ w_theta,
                                                const float* __restrict__ w_phi,
                                                const float* __restrict__ w_mask,
                                                unsigned short* __restrict__ wcat_bf) {
    __shared__ float t[4096];
    int tid = threadIdx.x;
#pragma unroll
    for (int i = 0; i < 4; ++i) {
        int idx = i * 1024 + tid;
        int d = idx >> 6, e = idx & 63;
        float acc = 0.f;
        for (int c = 0; c < 64; ++c) acc += w_mv[d * 64 + c] * w_g[c * 64 + e];
        t[idx] = acc;
        wcat_bf[idx] = f2bf(w_theta[idx]);
        wcat_bf[4096 + idx] = f2bf(w_phi[idx]);
    }
    __syncthreads();
#pragma unroll
    for (int i = 0; i < 4; ++i) {
        int idx = i * 1024 + tid;
        int d = idx >> 6, e = idx & 63;
        float acc = 0.f;
        for (int c = 0; c < 64; ++c) acc += w_mask[d * 64 + c] * t[c * 64 + e];
        wcat_bf[8192 + idx] = f2bf(acc);
    }
}

// ---------------------------------------------------------------------------
// k0b: w_mk (1M fp32) -> bf16, layout unchanged [k][m] (m contiguous).
// ---------------------------------------------------------------------------
__global__ void k0b_wmk(const float* __restrict__ wmk, unsigned short* __restrict__ wmk_bf) {
    int i = (blockIdx.x * 256 + threadIdx.x) * 4;
    float4 v = *(const float4*)(wmk + i);
    us4 r;
    r.x = f2bf(v.x); r.y = f2bf(v.y); r.z = f2bf(v.z); r.w = f2bf(v.w);
    *(us4*)(wmk_bf + i) = r;
}

// ---------------------------------------------------------------------------
// k1: channel GEMMs via MFMA: out[192][64-tile] = wcat @ x_tile (K=c=64).
// Outputs: theta_nc[b][n][c], phi_cm[b][c][n], g4raw_cm[b][o][n] (= wall@x).
// ---------------------------------------------------------------------------
__global__ __launch_bounds__(256, 4) void k1_channel(const float* __restrict__ x,
                                                     const unsigned short* __restrict__ wcat,
                                                     unsigned short* __restrict__ theta_nc,
                                                     unsigned short* __restrict__ phi_cm,
                                                     unsigned short* __restrict__ g4raw_cm) {
    __shared__ unsigned short xT[64][66];
    int b = blockIdx.y;
    int n0 = blockIdx.x * 64;
    int tid = threadIdx.x;
    int w = tid >> 6, lane = tid & 63, l16 = lane & 15, q = lane >> 4;
    size_t bo = (size_t)b * CC * NN;
#pragma unroll
    for (int i = 0; i < 16; ++i) {
        int idx = i * 256 + tid;
        int c = idx >> 6, n2 = idx & 63;
        xT[n2][c] = f2bf(x[bo + (size_t)c * NN + n0 + n2]);
    }
    __syncthreads();
    bf8 bF[4][2];
#pragma unroll
    for (int ct = 0; ct < 4; ++ct) {
        bF[ct][0] = *(const bf8*)&xT[ct * 16 + l16][q * 8];
        bF[ct][1] = *(const bf8*)&xT[ct * 16 + l16][32 + q * 8];
    }
#pragma unroll
    for (int rt = 0; rt < 3; ++rt) {
        int R = w * 48 + rt * 16;
        const unsigned short* wa = wcat + (R + l16) * 64 + q * 8;
        bf8 a0 = *(const bf8*)wa;
        bf8 a1 = *(const bf8*)(wa + 32);
        int which = R >> 6, rb = R & 63;  // wave-uniform
#pragma unroll
        for (int ct = 0; ct < 4; ++ct) {
            f4 acc = {0.f, 0.f, 0.f, 0.f};
            acc = MFMA(a0, bF[ct][0], acc);
            acc = MFMA(a1, bF[ct][1], acc);
            int n = n0 + ct * 16 + l16;
            if (which == 0) {  // theta: [n][c] layout
                us4 t;
                t.x = f2bf(acc[0]); t.y = f2bf(acc[1]);
                t.z = f2bf(acc[2]); t.w = f2bf(acc[3]);
                *(us4*)&theta_nc[bo + (size_t)n * 64 + rb + q * 4] = t;
            } else {
                unsigned short* dst = (which == 1 ? phi_cm : g4raw_cm) + bo;
#pragma unroll
                for (int r = 0; r < 4; ++r)
                    dst[(size_t)(rb + q * 4 + r) * NN + n] = f2bf(acc[r]);
            }
        }
    }
}

// ---------------------------------------------------------------------------
// k2: phi2t[b][k][c] = sum_m wmk[k][m] * phi_cm[c][m]  (MFMA, K=m=1024)
// 512 thr / 8 waves: (ks = w&3 -> 16 k-rows, mh = w>>2 -> m-half).
// DOUBLE-BUFFERED staging: GLDS for chunk i+1 issued right after the single
// per-iteration barrier, so the barrier's vmcnt drain waits on a DMA that has
// had a full iteration in flight. wmk rows register-prefetched.
// ---------------------------------------------------------------------------
__global__ __launch_bounds__(512, 4) void k2_phi2(const unsigned short* __restrict__ phi_cm,
                                                  const unsigned short* __restrict__ wmk_bf,
                                                  unsigned short* __restrict__ phi2t) {
    __shared__ unsigned short bT[2][2][4096];  // [mh][buf][c64 x m64]
    __shared__ float red[64][68];
    int b = blockIdx.y;
    int k0 = blockIdx.x * 64;
    int tid = threadIdx.x;
    int w = tid >> 6, lane = tid & 63, l16 = lane & 15, q = lane >> 4;
    int e8 = lane >> 3, c8 = (lane & 7) * 8;
    int ks = w & 3, mh = w >> 2;
    size_t bo = (size_t)b * CC * NN;
    const unsigned short* phib = phi_cm + bo;
    const unsigned short* arow = wmk_bf + (size_t)(k0 + ks * 16 + l16) * NN + q * 8;
    f4 acc[4];
#pragma unroll
    for (int tc = 0; tc < 4; ++tc) acc[tc] = (f4){0.f, 0.f, 0.f, 0.f};
    // preload chunk 0 (DMA + A regs)
    {
        const unsigned short* gg = phib + (size_t)(ks * 16 + e8) * NN + mh * 512 + c8;
        GLDS(gg, &bT[mh][0][ks * 1024]);
        GLDS(gg + (size_t)8 * NN, &bT[mh][0][ks * 1024 + 512]);
    }
    bf8 a0 = *(const bf8*)(arow + mh * 512);
    bf8 a1 = *(const bf8*)(arow + mh * 512 + 32);
    int d = 0;
#pragma unroll 1
    for (int mc = 0; mc < 8; ++mc) {
        __syncthreads();  // bT[mh][d] staged (DMA issued a full iteration ago)
        bf8 p0, p1;
        if (mc < 7) {
            int m1 = mh * 512 + (mc + 1) * 64;
            const unsigned short* gg = phib + (size_t)(ks * 16 + e8) * NN + m1 + c8;
            GLDS(gg, &bT[mh][d ^ 1][ks * 1024]);
            GLDS(gg + (size_t)8 * NN, &bT[mh][d ^ 1][ks * 1024 + 512]);
            p0 = *(const bf8*)(arow + m1);
            p1 = *(const bf8*)(arow + m1 + 32);
        }
#pragma unroll
        for (int tc = 0; tc < 4; ++tc) {
            bf8 b0 = *(const bf8*)&bT[mh][d][(tc * 16 + l16) * 64 + q * 8];
            bf8 b1 = *(const bf8*)&bT[mh][d][(tc * 16 + l16) * 64 + 32 + q * 8];
            acc[tc] = MFMA(a0, b0, acc[tc]);
            acc[tc] = MFMA(a1, b1, acc[tc]);
        }
        a0 = p0;
        a1 = p1;
        d ^= 1;
    }
    __syncthreads();
    if (mh == 1) {
#pragma unroll
        for (int tc = 0; tc < 4; ++tc)
#pragma unroll
            for (int r = 0; r < 4; ++r) red[ks * 16 + q * 4 + r][tc * 16 + l16] = acc[tc][r];
    }
    __syncthreads();
    if (mh == 0) {
        unsigned short* prow = phi2t + bo;
#pragma unroll
        for (int tc = 0; tc < 4; ++tc)
#pragma unroll
            for (int r = 0; r < 4; ++r) {
                float v = acc[tc][r] + red[ks * 16 + q * 4 + r][tc * 16 + l16];
                prow[(size_t)(k0 + ks * 16 + q * 4 + r) * 64 + tc * 16 + l16] = f2bf(v);
            }
    }
}

// ---------------------------------------------------------------------------
// k3: att[k][n] tiles = phi2t @ theta^T (K=c=64); Sinv[b][k] = 1/sum_n exp.
// No E store, no g-scale pass (Sinv folded into k4's exp). Persistent phi2t
// A-frags; theta streamed with register prefetch; no barriers in the loop.
// 512 thr / 8 waves: (wq = w&3 -> n offset, nh = w>>2 -> n-half).
// No max-sub: |att| <~ 45 << 88 (fp32 exp range).
// ---------------------------------------------------------------------------
__global__ __launch_bounds__(512, 4) void k3_stats(const unsigned short* __restrict__ theta_nc,
                                                   const unsigned short* __restrict__ phi2t,
                                                   float* __restrict__ Sinv) {
    __shared__ float sred[8][64];
    int b = blockIdx.y;
    int k0 = blockIdx.x * 64;
    int tid = threadIdx.x;
    int w = tid >> 6, lane = tid & 63, l16 = lane & 15, q = lane >> 4;
    int wq = w & 3, nh = w >> 2;
    size_t bo = (size_t)b * CC * NN;
    bf8 aF[4][2];
#pragma unroll
    for (int tc = 0; tc < 4; ++tc)
#pragma unroll
        for (int kc = 0; kc < 2; ++kc)
            aF[tc][kc] = *(const bf8*)(phi2t + bo + (size_t)(k0 + tc * 16 + l16) * 64 + kc * 32 + q * 8);
    float sacc[4][4];
#pragma unroll
    for (int tc = 0; tc < 4; ++tc)
#pragma unroll
        for (int r = 0; r < 4; ++r) sacc[tc][r] = 0.f;
    const unsigned short* thb = theta_nc + bo + q * 8;
    int nbase = nh * 8;
    int nrow0 = nbase * 64 + wq * 16 + l16;
    bf8 t0 = *(const bf8*)(thb + (size_t)nrow0 * 64);
    bf8 t1 = *(const bf8*)(thb + (size_t)nrow0 * 64 + 32);
    for (int nb = 0; nb < 8; ++nb) {
        bf8 p0, p1;
        if (nb < 7) {
            int nr = (nbase + nb + 1) * 64 + wq * 16 + l16;
            p0 = *(const bf8*)(thb + (size_t)nr * 64);
            p1 = *(const bf8*)(thb + (size_t)nr * 64 + 32);
        }
#pragma unroll
        for (int tc = 0; tc < 4; ++tc) {
            f4 acc = {0.f, 0.f, 0.f, 0.f};
            acc = MFMA(aF[tc][0], t0, acc);
            acc = MFMA(aF[tc][1], t1, acc);
            sacc[tc][0] += __expf(acc[0]);
            sacc[tc][1] += __expf(acc[1]);
            sacc[tc][2] += __expf(acc[2]);
            sacc[tc][3] += __expf(acc[3]);
        }
        t0 = p0;
        t1 = p1;
    }
    // sum over the 16 n-lanes (bits 0..3 of lane id)
#pragma unroll
    for (int tc = 0; tc < 4; ++tc)
#pragma unroll
        for (int r = 0; r < 4; ++r) {
            sacc[tc][r] += __shfl_xor(sacc[tc][r], 1, 64);
            sacc[tc][r] += __shfl_xor(sacc[tc][r], 2, 64);
            sacc[tc][r] += __shfl_xor(sacc[tc][r], 4, 64);
            sacc[tc][r] += __shfl_xor(sacc[tc][r], 8, 64);
        }
    if (l16 == 0) {
#pragma unroll
        for (int tc = 0; tc < 4; ++tc)
#pragma unroll
            for (int r = 0; r < 4; ++r) sred[w][tc * 16 + q * 4 + r] = sacc[tc][r];
    }
    __syncthreads();
    if (tid < 64) {
        float S = 0.f;
#pragma unroll
        for (int ww = 0; ww < 8; ++ww) S += sred[ww][tid];
        Sinv[(size_t)b * NN + k0 + tid] = 1.f / S;
    }
}

// ---------------------------------------------------------------------------
// k4: fused recompute: per (b, n-tile 64): attT[m][n] = phi2t @ theta^T,
// P = exp(attT)*Sinv[m] -> LDS (wave-private rows, no barrier),
// out[o][n] += g4raw[o][m-chunk] @ P^T; halves reduce via LDS; + x residual.
// phi2t staged via DOUBLE-BUFFERED GLDS (1 barrier/iter); g4raw rows loaded
// direct-to-register (latency hidden behind GEMM1+exp). wall folded in k1
// -> no epilogue GEMM.
// 512 thr / 8 waves: (ws = w&3 -> 16 n's, mh = w>>2 -> m-half).
// ---------------------------------------------------------------------------
__global__ __launch_bounds__(512, 4) void k4_out(const unsigned short* __restrict__ theta_nc,
                                                 const unsigned short* __restrict__ phi2t,
                                                 const unsigned short* __restrict__ g4raw,
                                                 const float* __restrict__ Sinv,
                                                 const float* __restrict__ x,
                                                 float* __restrict__ out) {
    __shared__ unsigned short stage[2][2][4096];  // [mh][buf][m64 x c64] phi2t tiles
    __shared__ unsigned short P_lds[2][64][72];
    int b = blockIdx.y;
    int n0 = blockIdx.x * 64;
    int tid = threadIdx.x;
    int w = tid >> 6, lane = tid & 63, l16 = lane & 15, q = lane >> 4;
    int e8 = lane >> 3, c8 = (lane & 7) * 8;
    int ws = w & 3, mh = w >> 2;
    int nl = ws * 16 + l16;  // lane's n (LDS row, frag col) — wave-private rows
    size_t bo = (size_t)b * CC * NN;
    const unsigned short* p2b = phi2t + bo;
    const unsigned short* gb = g4raw + bo;
    const float* svb = Sinv + (size_t)b * NN;
    bf8 thB[2];
#pragma unroll
    for (int kc = 0; kc < 2; ++kc)
        thB[kc] = *(const bf8*)(theta_nc + bo + (size_t)(n0 + nl) * 64 + kc * 32 + q * 8);
    f4 acc[4];
#pragma unroll
    for (int tr = 0; tr < 4; ++tr) acc[tr] = (f4){0.f, 0.f, 0.f, 0.f};
    // preload chunk 0 phi2t tile
    {
        int r = ws * 16 + e8;
        const unsigned short* ga = p2b + (size_t)(mh * 512 + r) * 64 + c8;
        GLDS(ga, &stage[mh][0][ws * 1024]);
        GLDS(ga + 8 * 64, &stage[mh][0][ws * 1024 + 512]);
    }
    int d = 0;
#pragma unroll 1
    for (int mc = 0; mc < 8; ++mc) {
        int m0 = mh * 512 + mc * 64;
        __syncthreads();  // stage[mh][d] ready (DMA had a full iteration in flight)
        if (mc < 7) {
            int r = ws * 16 + e8;
            const unsigned short* ga = p2b + (size_t)(m0 + 64 + r) * 64 + c8;
            GLDS(ga, &stage[mh][d ^ 1][ws * 1024]);
            GLDS(ga + 8 * 64, &stage[mh][d ^ 1][ws * 1024 + 512]);
        }
        // g4raw frags: wave-private direct loads, hidden behind GEMM1+exp
        bf8 g0[4], g1[4];
#pragma unroll
        for (int tr = 0; tr < 4; ++tr) {
            const unsigned short* gg = gb + (size_t)(tr * 16 + l16) * NN + m0 + q * 8;
            g0[tr] = *(const bf8*)gg;
            g1[tr] = *(const bf8*)(gg + 32);
        }
        // GEMM1: attT tile (rows m, cols n); P = exp * Sinv[m] -> P_lds[n][m]
        const unsigned short* aT = &stage[mh][d][0];
#pragma unroll
        for (int tr = 0; tr < 4; ++tr) {
            int row = (tr * 16 + l16) * 64;
            bf8 a0 = *(const bf8*)&aT[row + q * 8];
            bf8 a1 = *(const bf8*)&aT[row + 32 + q * 8];
            f4 at = {0.f, 0.f, 0.f, 0.f};
            at = MFMA(a0, thB[0], at);
            at = MFMA(a1, thB[1], at);
            float4 sv = *(const float4*)(svb + m0 + tr * 16 + q * 4);
            us4 pk;
            pk.x = f2bf(__expf(at[0]) * sv.x);
            pk.y = f2bf(__expf(at[1]) * sv.y);
            pk.z = f2bf(__expf(at[2]) * sv.z);
            pk.w = f2bf(__expf(at[3]) * sv.w);
            *(us4*)&P_lds[mh][nl][tr * 16 + q * 4] = pk;
        }
        // GEMM2: out[o][n] += g4raw[o][m] * P[n][m]
        bf8 pF0 = *(const bf8*)&P_lds[mh][nl][q * 8];
        bf8 pF1 = *(const bf8*)&P_lds[mh][nl][32 + q * 8];
#pragma unroll
        for (int tr = 0; tr < 4; ++tr) {
            acc[tr] = MFMA(g0[tr], pF0, acc[tr]);
            acc[tr] = MFMA(g1[tr], pF1, acc[tr]);
        }
        d ^= 1;
    }
    // reduce the two m-halves (red aliases stage — barrier first)
    __syncthreads();
    float (*red)[68] = (float(*)[68])(void*)stage;  // 17.4 KB <= 32 KB stage
    if (mh == 1) {
#pragma unroll
        for (int tr = 0; tr < 4; ++tr)
#pragma unroll
            for (int r = 0; r < 4; ++r) red[tr * 16 + q * 4 + r][nl] = acc[tr][r];
    }
    __syncthreads();
    if (mh == 0) {
#pragma unroll
        for (int tr = 0; tr < 4; ++tr)
#pragma unroll
            for (int r = 0; r < 4; ++r) {
                int o = tr * 16 + q * 4 + r;
                size_t ix = bo + (size_t)o * NN + n0 + nl;
                out[ix] = acc[tr][r] + red[o][nl] + x[ix];
            }
    }
}

// ---------------------------------------------------------------------------
extern "C" void kernel_launch(void* const* d_in, const int* in_sizes, int n_in,
                              void* d_out, int out_size, void* d_ws, size_t ws_size,
                              hipStream_t stream) {
    const float* x       = (const float*)d_in[0];
    const float* w_phi   = (const float*)d_in[1];
    const float* w_theta = (const float*)d_in[2];
    const float* w_g     = (const float*)d_in[3];
    const float* w_mask  = (const float*)d_in[4];
    const float* w_mv    = (const float*)d_in[5];
    const float* w_mk    = (const float*)d_in[6];
    float* out = (float*)d_out;

    const size_t CN = (size_t)BB * CC * NN;  // 2,097,152 elements
    char* p = (char*)d_ws;
    unsigned short* theta_nc = (unsigned short*)p; p += CN * 2;
    unsigned short* phi_cm = (unsigned short*)p;   p += CN * 2;
    unsigned short* g4raw = (unsigned short*)p;    p += CN * 2;
    unsigned short* phi2t = (unsigned short*)p;    p += CN * 2;
    unsigned short* wmk_bf = (unsigned short*)p;   p += (size_t)NN * NN * 2;
    unsigned short* wcat_bf = (unsigned short*)p;  p += 192 * 64 * 2;
    float* Sinv = (float*)p;                       p += (size_t)BB * NN * sizeof(float);

    k0_prep<<<1, 1024, 0, stream>>>(w_mv, w_g, w_theta, w_phi, w_mask, wcat_bf);
    k0b_wmk<<<1024, 256, 0, stream>>>(w_mk, wmk_bf);
    k1_channel<<<dim3(16, BB), 256, 0, stream>>>(x, wcat_bf, theta_nc, phi_cm, g4raw);
    k2_phi2<<<dim3(16, BB), 512, 0, stream>>>(phi_cm, wmk_bf, phi2t);
    k3_stats<<<dim3(16, BB), 512, 0, stream>>>(theta_nc, phi2t, Sinv);
    k4_out<<<dim3(16, BB), 512, 0, stream>>>(theta_nc, phi2t, g4raw, Sinv, x, out);
}

// Round 9
// 158.298 us; speedup vs baseline: 1.1775x; 1.1775x over previous
//
#include <hip/hip_runtime.h>

#define BB 32
#define CC 64
#define NN 1024

typedef __attribute__((ext_vector_type(8))) short bf8;            // 8 bf16 = 4 VGPR (MFMA A/B frag)
typedef __attribute__((ext_vector_type(4))) float f4;             // MFMA C/D frag
typedef __attribute__((ext_vector_type(4))) unsigned short us4;   // 8B packed bf16 store

__device__ __forceinline__ unsigned short f2bf(float f) {
    unsigned u = __float_as_uint(f);
    return (unsigned short)((u + 0x7fffu + ((u >> 16) & 1u)) >> 16);
}
__device__ __forceinline__ float bf2f(unsigned short u) {
    return __uint_as_float(((unsigned)u) << 16);
}

#define MFMA(a, b, c) __builtin_amdgcn_mfma_f32_16x16x32_bf16(a, b, c, 0, 0, 0)

// Async global->LDS DMA, 16 B per lane: LDS dst = wave-uniform base + lane*16.
#define GLDS(g, l)                                                              \
    __builtin_amdgcn_global_load_lds(                                           \
        (const __attribute__((address_space(1))) void*)(g),                     \
        (__attribute__((address_space(3))) void*)(l), 16, 0, 0)

// ---------------------------------------------------------------------------
// k0: wcat_bf[192][64] = [w_theta; w_phi; wall] bf16, where
// wall = w_mask @ w_mv @ w_g (mask epilogue folded through mv,g).
// ---------------------------------------------------------------------------
__global__ __launch_bounds__(1024) void k0_prep(const float* __restrict__ w_mv,
                                                const float* __restrict__ w_g,
                                                const float* __restrict__ w_theta,
                                                const float* __restrict__ w_phi,
                                                const float* __restrict__ w_mask,
                                                unsigned short* __restrict__ wcat_bf) {
    __shared__ float t[4096];
    int tid = threadIdx.x;
#pragma unroll
    for (int i = 0; i < 4; ++i) {
        int idx = i * 1024 + tid;
        int d = idx >> 6, e = idx & 63;
        float acc = 0.f;
        for (int c = 0; c < 64; ++c) acc += w_mv[d * 64 + c] * w_g[c * 64 + e];
        t[idx] = acc;
        wcat_bf[idx] = f2bf(w_theta[idx]);
        wcat_bf[4096 + idx] = f2bf(w_phi[idx]);
    }
    __syncthreads();
#pragma unroll
    for (int i = 0; i < 4; ++i) {
        int idx = i * 1024 + tid;
        int d = idx >> 6, e = idx & 63;
        float acc = 0.f;
        for (int c = 0; c < 64; ++c) acc += w_mask[d * 64 + c] * t[c * 64 + e];
        wcat_bf[8192 + idx] = f2bf(acc);
    }
}

// ---------------------------------------------------------------------------
// k0b: w_mk (1M fp32) -> bf16, layout unchanged [k][m] (m contiguous).
// ---------------------------------------------------------------------------
__global__ void k0b_wmk(const float* __restrict__ wmk, unsigned short* __restrict__ wmk_bf) {
    int i = (blockIdx.x * 256 + threadIdx.x) * 4;
    float4 v = *(const float4*)(wmk + i);
    us4 r;
    r.x = f2bf(v.x); r.y = f2bf(v.y); r.z = f2bf(v.z); r.w = f2bf(v.w);
    *(us4*)(wmk_bf + i) = r;
}

// ---------------------------------------------------------------------------
// k1: channel GEMMs via MFMA: out[192][64-tile] = wcat @ x_tile (K=c=64).
// Outputs: theta_nc[b][n][c], phi_cm[b][c][n], g4raw_cm[b][o][n] (= wall@x).
// ---------------------------------------------------------------------------
__global__ __launch_bounds__(256, 4) void k1_channel(const float* __restrict__ x,
                                                     const unsigned short* __restrict__ wcat,
                                                     unsigned short* __restrict__ theta_nc,
                                                     unsigned short* __restrict__ phi_cm,
                                                     unsigned short* __restrict__ g4raw_cm) {
    __shared__ unsigned short xT[64][66];
    int b = blockIdx.y;
    int n0 = blockIdx.x * 64;
    int tid = threadIdx.x;
    int w = tid >> 6, lane = tid & 63, l16 = lane & 15, q = lane >> 4;
    size_t bo = (size_t)b * CC * NN;
#pragma unroll
    for (int i = 0; i < 16; ++i) {
        int idx = i * 256 + tid;
        int c = idx >> 6, n2 = idx & 63;
        xT[n2][c] = f2bf(x[bo + (size_t)c * NN + n0 + n2]);
    }
    __syncthreads();
    bf8 bF[4][2];
#pragma unroll
    for (int ct = 0; ct < 4; ++ct) {
        bF[ct][0] = *(const bf8*)&xT[ct * 16 + l16][q * 8];
        bF[ct][1] = *(const bf8*)&xT[ct * 16 + l16][32 + q * 8];
    }
#pragma unroll
    for (int rt = 0; rt < 3; ++rt) {
        int R = w * 48 + rt * 16;
        const unsigned short* wa = wcat + (R + l16) * 64 + q * 8;
        bf8 a0 = *(const bf8*)wa;
        bf8 a1 = *(const bf8*)(wa + 32);
        int which = R >> 6, rb = R & 63;  // wave-uniform
#pragma unroll
        for (int ct = 0; ct < 4; ++ct) {
            f4 acc = {0.f, 0.f, 0.f, 0.f};
            acc = MFMA(a0, bF[ct][0], acc);
            acc = MFMA(a1, bF[ct][1], acc);
            int n = n0 + ct * 16 + l16;
            if (which == 0) {  // theta: [n][c] layout
                us4 t;
                t.x = f2bf(acc[0]); t.y = f2bf(acc[1]);
                t.z = f2bf(acc[2]); t.w = f2bf(acc[3]);
                *(us4*)&theta_nc[bo + (size_t)n * 64 + rb + q * 4] = t;
            } else {
                unsigned short* dst = (which == 1 ? phi_cm : g4raw_cm) + bo;
#pragma unroll
                for (int r = 0; r < 4; ++r)
                    dst[(size_t)(rb + q * 4 + r) * NN + n] = f2bf(acc[r]);
            }
        }
    }
}

// ---------------------------------------------------------------------------
// k2: phi2t[b][k][c] = sum_m wmk[k][m] * phi_cm[c][m]  (MFMA, K=m=1024)
// 512 thr / 8 waves: (ks = w&3 -> 16 k-rows, mh = w>>2 -> m-half).
// Single-buffered GLDS staging (R5-proven); wmk rows direct to regs.
// ---------------------------------------------------------------------------
__global__ __launch_bounds__(512, 4) void k2_phi2(const unsigned short* __restrict__ phi_cm,
                                                  const unsigned short* __restrict__ wmk_bf,
                                                  unsigned short* __restrict__ phi2t) {
    __shared__ unsigned short bT[2][4096];
    __shared__ float red[64][68];
    int b = blockIdx.y;
    int k0 = blockIdx.x * 64;
    int tid = threadIdx.x;
    int w = tid >> 6, lane = tid & 63, l16 = lane & 15, q = lane >> 4;
    int e8 = lane >> 3, c8 = (lane & 7) * 8;
    int ks = w & 3, mh = w >> 2;
    size_t bo = (size_t)b * CC * NN;
    const unsigned short* phib = phi_cm + bo;
    const unsigned short* arow = wmk_bf + (size_t)(k0 + ks * 16 + l16) * NN + q * 8;
    f4 acc[4];
#pragma unroll
    for (int tc = 0; tc < 4; ++tc) acc[tc] = (f4){0.f, 0.f, 0.f, 0.f};

#pragma unroll 1
    for (int mc = 0; mc < 8; ++mc) {
        int m0 = mh * 512 + mc * 64;
        bf8 a0 = *(const bf8*)(arow + m0);
        bf8 a1 = *(const bf8*)(arow + m0 + 32);
        __syncthreads();
        const unsigned short* gg = phib + (size_t)(ks * 16 + e8) * NN + m0 + c8;
        GLDS(gg, &bT[mh][ks * 1024]);
        GLDS(gg + (size_t)8 * NN, &bT[mh][ks * 1024 + 512]);
        __syncthreads();
#pragma unroll
        for (int tc = 0; tc < 4; ++tc) {
            bf8 b0 = *(const bf8*)&bT[mh][(tc * 16 + l16) * 64 + q * 8];
            bf8 b1 = *(const bf8*)&bT[mh][(tc * 16 + l16) * 64 + 32 + q * 8];
            acc[tc] = MFMA(a0, b0, acc[tc]);
            acc[tc] = MFMA(a1, b1, acc[tc]);
        }
    }
    __syncthreads();
    if (mh == 1) {
#pragma unroll
        for (int tc = 0; tc < 4; ++tc)
#pragma unroll
            for (int r = 0; r < 4; ++r) red[ks * 16 + q * 4 + r][tc * 16 + l16] = acc[tc][r];
    }
    __syncthreads();
    if (mh == 0) {
        unsigned short* prow = phi2t + bo;
#pragma unroll
        for (int tc = 0; tc < 4; ++tc)
#pragma unroll
            for (int r = 0; r < 4; ++r) {
                float v = acc[tc][r] + red[ks * 16 + q * 4 + r][tc * 16 + l16];
                prow[(size_t)(k0 + ks * 16 + q * 4 + r) * 64 + tc * 16 + l16] = f2bf(v);
            }
    }
}

// ---------------------------------------------------------------------------
// k3: S[k] = sum_n exp(att2[n][k]), att2 = theta @ phi2t^T (K=64), then
// g4[o][k] = g4raw[o][k] * (1/S[k])  (fold Sinv into g; block owns its m's).
// 512 thr / 8 waves: (wq -> n offset, nh -> n-half); theta register prefetch.
// No max subtraction: |att2| <~ 45 << 88 (fp32 exp range).
// ---------------------------------------------------------------------------
__global__ __launch_bounds__(512, 4) void k3_stats(const unsigned short* __restrict__ theta_nc,
                                                   const unsigned short* __restrict__ phi2t,
                                                   const unsigned short* __restrict__ g4raw,
                                                   unsigned short* __restrict__ g4) {
    __shared__ float sred[8][64];
    __shared__ float svs[64];
    int b = blockIdx.y;
    int k0 = blockIdx.x * 64;
    int tid = threadIdx.x;
    int w = tid >> 6, lane = tid & 63, l16 = lane & 15, q = lane >> 4;
    int wq = w & 3, nh = w >> 2;
    size_t bo = (size_t)b * CC * NN;
    bf8 bF[4][2];
#pragma unroll
    for (int tc = 0; tc < 4; ++tc)
#pragma unroll
        for (int kc = 0; kc < 2; ++kc)
            bF[tc][kc] = *(const bf8*)(phi2t + bo + (size_t)(k0 + tc * 16 + l16) * 64 + kc * 32 + q * 8);
    float s[4] = {0.f, 0.f, 0.f, 0.f};
    const unsigned short* thb = theta_nc + bo + q * 8;
    int nbase = nh * 8;
    int nrow0 = nbase * 64 + wq * 16 + l16;
    bf8 a0 = *(const bf8*)(thb + (size_t)nrow0 * 64);
    bf8 a1 = *(const bf8*)(thb + (size_t)nrow0 * 64 + 32);
    for (int nb = 0; nb < 8; ++nb) {
        bf8 p0, p1;
        if (nb < 7) {  // prefetch next chunk while computing this one
            int nr = (nbase + nb + 1) * 64 + wq * 16 + l16;
            p0 = *(const bf8*)(thb + (size_t)nr * 64);
            p1 = *(const bf8*)(thb + (size_t)nr * 64 + 32);
        }
#pragma unroll
        for (int tc = 0; tc < 4; ++tc) {
            f4 acc = {0.f, 0.f, 0.f, 0.f};
            acc = MFMA(a0, bF[tc][0], acc);
            acc = MFMA(a1, bF[tc][1], acc);
            s[tc] += __expf(acc[0]) + __expf(acc[1]) + __expf(acc[2]) + __expf(acc[3]);
        }
        a0 = p0;
        a1 = p1;
    }
#pragma unroll
    for (int tc = 0; tc < 4; ++tc) {
        s[tc] += __shfl_xor(s[tc], 16, 64);
        s[tc] += __shfl_xor(s[tc], 32, 64);
    }
    if (q == 0) {
#pragma unroll
        for (int tc = 0; tc < 4; ++tc) sred[w][tc * 16 + l16] = s[tc];
    }
    __syncthreads();
    if (tid < 64) {
        float S = 0.f;
#pragma unroll
        for (int ww = 0; ww < 8; ++ww) S += sred[ww][tid];
        svs[tid] = 1.f / S;
    }
    __syncthreads();
    int c0 = tid >> 6, kl = tid & 63;
#pragma unroll
    for (int i = 0; i < 8; ++i) {
        int c = c0 * 8 + i;
        size_t ix = bo + (size_t)c * NN + k0 + kl;
        g4[ix] = f2bf(bf2f(g4raw[ix]) * svs[kl]);
    }
}

// ---------------------------------------------------------------------------
// k4: per (b, n-tile 64): attT[m][n] = phi2t @ theta^T, P = exp(attT) (Sinv
// already in g4), P -> LDS (wave-private rows); out[o][n] += g4 @ P^T; halves
// reduce via LDS fp32; direct write + x residual (wall folded -> no epilogue).
// phi2t/g4 tiles staged via single-buffered GLDS (R5-proven structure).
// 512 thr / 8 waves: (ws = w&3 -> 16 n's, mh = w>>2 -> m-half).
// ---------------------------------------------------------------------------
__global__ __launch_bounds__(512, 4) void k4_out(const unsigned short* __restrict__ theta_nc,
                                                 const unsigned short* __restrict__ phi2t,
                                                 const unsigned short* __restrict__ g4,
                                                 const float* __restrict__ x,
                                                 float* __restrict__ out) {
    __shared__ unsigned short stage[16384];  // aT[mh]=+mh*4096, gT[mh]=+8192+mh*4096
    __shared__ unsigned short P_lds[2][64][72];
    int b = blockIdx.y;
    int n0 = blockIdx.x * 64;
    int tid = threadIdx.x;
    int w = tid >> 6, lane = tid & 63, l16 = lane & 15, q = lane >> 4;
    int e8 = lane >> 3, c8 = (lane & 7) * 8;
    int ws = w & 3, mh = w >> 2;
    int nl = ws * 16 + l16;  // lane's n (LDS row, frag col) — wave-private rows
    size_t bo = (size_t)b * CC * NN;
    unsigned short* aT = stage + mh * 4096;         // phi2t chunk [m_local][c]
    unsigned short* gT = stage + 8192 + mh * 4096;  // g4 chunk [o][m_local]
    bf8 thB[2];
#pragma unroll
    for (int kc = 0; kc < 2; ++kc)
        thB[kc] = *(const bf8*)(theta_nc + bo + (size_t)(n0 + nl) * 64 + kc * 32 + q * 8);
    f4 acc[4];
#pragma unroll
    for (int tr = 0; tr < 4; ++tr) acc[tr] = (f4){0.f, 0.f, 0.f, 0.f};
    const unsigned short* p2b = phi2t + bo;
    const unsigned short* g4b = g4 + bo;

#pragma unroll 1
    for (int mc = 0; mc < 8; ++mc) {
        int m0 = mh * 512 + mc * 64;
        __syncthreads();  // prior readers of this half's tiles done
        {
            int r = ws * 16 + e8;
            const unsigned short* ga = p2b + (size_t)(m0 + r) * 64 + c8;
            GLDS(ga, aT + ws * 1024);
            GLDS(ga + 8 * 64, aT + ws * 1024 + 512);
            const unsigned short* gg = g4b + (size_t)r * NN + m0 + c8;
            GLDS(gg, gT + ws * 1024);
            GLDS(gg + (size_t)8 * NN, gT + ws * 1024 + 512);
        }
        __syncthreads();  // drains vmcnt: both tiles staged
        // GEMM1: attT tile (rows m, cols n) ; exp -> P_lds[mh][n][m-local]
#pragma unroll
        for (int tr = 0; tr < 4; ++tr) {
            int row = (tr * 16 + l16) * 64;
            bf8 a0 = *(const bf8*)&aT[row + q * 8];
            bf8 a1 = *(const bf8*)&aT[row + 32 + q * 8];
            f4 at = {0.f, 0.f, 0.f, 0.f};
            at = MFMA(a0, thB[0], at);
            at = MFMA(a1, thB[1], at);
            us4 pk;
            pk.x = f2bf(__expf(at[0]));
            pk.y = f2bf(__expf(at[1]));
            pk.z = f2bf(__expf(at[2]));
            pk.w = f2bf(__expf(at[3]));
            *(us4*)&P_lds[mh][nl][tr * 16 + q * 4] = pk;
        }
        // GEMM2: out[o][n] += sum_m g4[o][m] * P[n][m]
        bf8 pF0 = *(const bf8*)&P_lds[mh][nl][q * 8];
        bf8 pF1 = *(const bf8*)&P_lds[mh][nl][32 + q * 8];
#pragma unroll
        for (int tr = 0; tr < 4; ++tr) {
            int row = (tr * 16 + l16) * 64;
            bf8 g0 = *(const bf8*)&gT[row + q * 8];
            bf8 g1 = *(const bf8*)&gT[row + 32 + q * 8];
            acc[tr] = MFMA(g0, pF0, acc[tr]);
            acc[tr] = MFMA(g1, pF1, acc[tr]);
        }
    }
    // reduce the two m-halves (red aliases the stage region — barrier first)
    __syncthreads();
    float (*red)[68] = (float(*)[68])(void*)stage;  // 64x68 f32 = 17.4 KB <= 32 KB
    if (mh == 1) {
#pragma unroll
        for (int tr = 0; tr < 4; ++tr)
#pragma unroll
            for (int r = 0; r < 4; ++r) red[tr * 16 + q * 4 + r][nl] = acc[tr][r];
    }
    __syncthreads();
    if (mh == 0) {
#pragma unroll
        for (int tr = 0; tr < 4; ++tr)
#pragma unroll
            for (int r = 0; r < 4; ++r) {
                int o = tr * 16 + q * 4 + r;
                size_t ix = bo + (size_t)o * NN + n0 + nl;
                out[ix] = acc[tr][r] + red[o][nl] + x[ix];
            }
    }
}

// ---------------------------------------------------------------------------
extern "C" void kernel_launch(void* const* d_in, const int* in_sizes, int n_in,
                              void* d_out, int out_size, void* d_ws, size_t ws_size,
                              hipStream_t stream) {
    const float* x       = (const float*)d_in[0];
    const float* w_phi   = (const float*)d_in[1];
    const float* w_theta = (const float*)d_in[2];
    const float* w_g     = (const float*)d_in[3];
    const float* w_mask  = (const float*)d_in[4];
    const float* w_mv    = (const float*)d_in[5];
    const float* w_mk    = (const float*)d_in[6];
    float* out = (float*)d_out;

    const size_t CN = (size_t)BB * CC * NN;  // 2,097,152 elements
    char* p = (char*)d_ws;
    unsigned short* theta_nc = (unsigned short*)p; p += CN * 2;
    unsigned short* phi_cm = (unsigned short*)p;   p += CN * 2;
    unsigned short* g4raw = (unsigned short*)p;    p += CN * 2;
    unsigned short* g4 = (unsigned short*)p;       p += CN * 2;
    unsigned short* phi2t = (unsigned short*)p;    p += CN * 2;
    unsigned short* wmk_bf = (unsigned short*)p;   p += (size_t)NN * NN * 2;
    unsigned short* wcat_bf = (unsigned short*)p;  p += 192 * 64 * 2;

    k0_prep<<<1, 1024, 0, stream>>>(w_mv, w_g, w_theta, w_phi, w_mask, wcat_bf);
    k0b_wmk<<<1024, 256, 0, stream>>>(w_mk, wmk_bf);
    k1_channel<<<dim3(16, BB), 256, 0, stream>>>(x, wcat_bf, theta_nc, phi_cm, g4raw);
    k2_phi2<<<dim3(16, BB), 512, 0, stream>>>(phi_cm, wmk_bf, phi2t);
    k3_stats<<<dim3(16, BB), 512, 0, stream>>>(theta_nc, phi2t, g4raw, g4);
    k4_out<<<dim3(16, BB), 512, 0, stream>>>(theta_nc, phi2t, g4, x, out);
}